// Round 5
// baseline (104.782 us; speedup 1.0000x reference)
//
#include <hip/hip_runtime.h>
#include <math.h>

#define M_ 48
#define L_ 48
#define N_ 256
#define THREADS 512
#define NWAVE (THREADS/64)
#define NPAIR_UT 1176          // upper triangle incl. diagonal
#define PPT 3                  // ceil(1176/512) pairs per thread (dummies weight 0)

// One block (512 threads = 8 waves) per sample -> 2 waves/SIMD for latency
// hiding (R4's 256-thread config left 1 wave/SIMD: 60% stall time).
// Per-pair combined prefix G[p]=gm*gk; suffix checkpoints every 8 sites in
// registers + per-segment expansion R[8][PPT]; 2-step speculative evaluation
// -> ONE barrier per TWO measurements (24 rounds). Division-free decisions.
__launch_bounds__(THREADS, 2)
__global__ void mps_sample_kernel(const float* __restrict__ inp,
                                  const float* __restrict__ theta,
                                  const float* __restrict__ coef,
                                  const float* __restrict__ rand_u,
                                  float* __restrict__ out)
{
    const int n   = blockIdx.x;
    const int tid = threadIdx.x;

    __shared__ double s_pxy[L_][M_][2];      // (px,py) interleaved, b128-readable
    __shared__ double s_part[2][NWAVE][4];   // cross-wave partials, parity dbuf
    __shared__ float  s_u[L_];

    const double PI_2 = 1.5707963267948966;

    // ---- trig init: pxy[l][m] = coef[m] * (cos, sin)(theta + inp*(m+1)*pi/2) ----
    #pragma unroll
    for (int i = 0; i < 5; ++i) {
        int j = tid + THREADS * i;
        if (j < L_ * M_) {
            int l = j / M_, m = j - l * M_;
            double a  = (double)inp[n * L_ + l] * ((double)(m + 1) * PI_2);
            double th = (double)theta[l * M_ + m];
            double sv, cv; sincos(th + a, &sv, &cv);
            double cf = (double)coef[m];
            s_pxy[l][m][0] = cf * cv;
            s_pxy[l][m][1] = cf * sv;
        }
    }
    if (tid < L_) s_u[tid] = rand_u[tid * N_ + n];

    // ---- strided upper-triangle pair decode ----
    int pm[PPT], pk[PPT];
    double wgt[PPT];
    #pragma unroll
    for (int i = 0; i < PPT; ++i) {
        int p = tid + THREADS * i;
        if (p < NPAIR_UT) {
            int m = 0, r = p;
            while (r >= M_ - m) { r -= M_ - m; ++m; }
            pm[i] = m; pk[i] = m + r;
            wgt[i] = (r == 0) ? 1.0 : 2.0;
        } else { pm[i] = 0; pk[i] = 0; wgt[i] = 0.0; }
    }
    __syncthreads();

    // ---- register checkpoints: ckpt[s] = w * prod_{l'>=8(s+1)} T_l' ----
    double ckpt[5][PPT];
    {
        double C[PPT];
        #pragma unroll
        for (int i = 0; i < PPT; ++i) C[i] = wgt[i];
        #pragma unroll
        for (int s = 4; s >= 0; --s) {
            #pragma unroll
            for (int lp = 7; lp >= 0; --lp) {
                int l = 8 * (s + 1) + lp;              // 47 .. 8
                #pragma unroll
                for (int i = 0; i < PPT; ++i) {
                    double2 vm = *(const double2*)&s_pxy[l][pm[i]][0];
                    double2 vk = *(const double2*)&s_pxy[l][pk[i]][0];
                    C[i] *= vm.x * vk.x + vm.y * vk.y;
                }
            }
            #pragma unroll
            for (int i = 0; i < PPT; ++i) ckpt[s][i] = C[i];
        }
    }

    double G[PPT];
    #pragma unroll
    for (int i = 0; i < PPT; ++i) G[i] = 1.0;

    double denom = 0.0, initd = 1.0;
    float  myBit = 0.0f;

    #pragma unroll
    for (int seg = 0; seg < 6; ++seg) {
        // ---- register expansion R[j] = w * S_{8seg+j+1} ----
        double R[8][PPT], Crun[PPT];
        #pragma unroll
        for (int i = 0; i < PPT; ++i)
            Crun[i] = (seg == 5) ? wgt[i] : ckpt[seg == 5 ? 0 : seg][i];
        #pragma unroll
        for (int j = 7; j >= 0; --j) {
            #pragma unroll
            for (int i = 0; i < PPT; ++i) R[j][i] = Crun[i];
            if (j > 0) {
                int l2 = 8 * seg + j;
                #pragma unroll
                for (int i = 0; i < PPT; ++i) {
                    double2 vm = *(const double2*)&s_pxy[l2][pm[i]][0];
                    double2 vk = *(const double2*)&s_pxy[l2][pk[i]][0];
                    Crun[i] *= vm.x * vk.x + vm.y * vk.y;
                }
            }
        }

        // ---- 4 iterations x 2 speculative steps ----
        #pragma unroll
        for (int half = 0; half < 4; ++half) {
            const int ls  = 2 * half;
            const int l   = 8 * seg + ls;
            const int par = half & 1;
            double X0[PPT], Y0[PPT], X1[PPT], Y1[PPT];
            double n1L = 0.0, h0 = 0.0, h1 = 0.0, nT = 0.0;
            #pragma unroll
            for (int i = 0; i < PPT; ++i) {
                double2 vm0 = *(const double2*)&s_pxy[l][pm[i]][0];
                double2 vk0 = *(const double2*)&s_pxy[l][pk[i]][0];
                double2 vm1 = *(const double2*)&s_pxy[l + 1][pm[i]][0];
                double2 vk1 = *(const double2*)&s_pxy[l + 1][pk[i]][0];
                X0[i] = vm0.x * vk0.x;  Y0[i] = vm0.y * vk0.y;
                X1[i] = vm1.x * vk1.x;  Y1[i] = vm1.y * vk1.y;
                double t0 = G[i] * R[ls][i];
                double t1 = G[i] * R[ls + 1][i];
                n1L = fma(t0, Y0[i], n1L);
                if (seg == 0 && half == 0) nT = fma(t0, X0[i], nT); // denom seed
                h0 = fma(t1 * X0[i], Y1[i], h0);          // hypothesis bit_l = 0
                h1 = fma(t1 * Y0[i], Y1[i], h1);          // hypothesis bit_l = 1
            }
            // butterfly: every lane ends with the identical full wave sum
            #pragma unroll
            for (int off = 1; off < 64; off <<= 1) {
                n1L += __shfl_xor(n1L, off, 64);
                h0  += __shfl_xor(h0,  off, 64);
                h1  += __shfl_xor(h1,  off, 64);
                if (seg == 0 && half == 0) nT += __shfl_xor(nT, off, 64);
            }
            const int wv = tid >> 6;
            if ((tid & 63) == 0) {
                s_part[par][wv][0] = n1L; s_part[par][wv][1] = h0;
                s_part[par][wv][2] = h1;  s_part[par][wv][3] = nT;
            }
            __syncthreads();
            double sn1 = 0.0, sh0 = 0.0, sh1 = 0.0;
            #pragma unroll
            for (int w = 0; w < NWAVE; ++w) {
                sn1 += s_part[par][w][0];
                sh0 += s_part[par][w][1];
                sh1 += s_part[par][w][2];
            }
            if (seg == 0 && half == 0) {
                double snT = 0.0;
                #pragma unroll
                for (int w = 0; w < NWAVE; ++w) snT += s_part[par][w][3];
                denom = fabs(snT + sn1);
                initd = denom;
            }
            // two bit decisions, division-free (denom = <psi|psi> > 0)
            double a1  = fabs(sn1);
            int bitA   = ((double)s_u[l] * denom < a1) ? 1 : 0;
            denom      = bitA ? a1 : fabs(denom - sn1);
            double n1b = bitA ? sh1 : sh0;
            double a2  = fabs(n1b);
            int bitB   = ((double)s_u[l + 1] * denom < a2) ? 1 : 0;
            denom      = bitB ? a2 : fabs(denom - n1b);
            // fused two-step prefix update
            #pragma unroll
            for (int i = 0; i < PPT; ++i) {
                double c0 = bitA ? Y0[i] : X0[i];
                double c1 = bitB ? Y1[i] : X1[i];
                G[i] *= c0 * c1;
            }
            if (tid == l)     myBit = (float)bitA;
            if (tid == l + 1) myBit = (float)bitB;
        }
    }

    if (tid < L_)  out[n * L_ + tid] = myBit;                 // bits, one burst
    if (tid == 0)  out[N_ * L_ + n] = (float)(denom / initd); // P_m carried free
}

extern "C" void kernel_launch(void* const* d_in, const int* in_sizes, int n_in,
                              void* d_out, int out_size, void* d_ws, size_t ws_size,
                              hipStream_t stream) {
    const float* inp    = (const float*)d_in[0];   // (N,L)
    const float* theta  = (const float*)d_in[1];   // (L,M)
    const float* coef   = (const float*)d_in[2];   // (M,)
    const float* rand_u = (const float*)d_in[3];   // (L,N)
    float* out = (float*)d_out;                    // N*L bits then N probs
    mps_sample_kernel<<<N_, THREADS, 0, stream>>>(inp, theta, coef, rand_u, out);
}

// Round 6
// 95.311 us; speedup vs baseline: 1.0994x; 1.0994x over previous
//
#include <hip/hip_runtime.h>
#include <math.h>

#define M_ 48
#define L_ 48
#define N_ 256
#define THREADS 256
#define NWAVE (THREADS/64)
#define NPAIR_UT 1176          // upper triangle incl. diagonal
#define PPT 5                  // pairs per thread (strided), tail slots weight 0

// One block (256 thr = 4 waves, 1/SIMD) per sample. Per-pair combined prefix
// G[p]; suffix checkpoints every 8 sites in registers; per-segment X/Y
// register stash makes all 24 measurement rounds LDS-free (R4 post-mortem:
// ~2k cyc/round of dependent ds_read stall). 2-step speculation -> one
// barrier per two measurements. Division-free decisions. ~360 VGPRs by
// design (launch_bounds(256,1) allows 512; 1 block/CU structurally).
__launch_bounds__(THREADS, 1)
__global__ void mps_sample_kernel(const float* __restrict__ inp,
                                  const float* __restrict__ theta,
                                  const float* __restrict__ coef,
                                  const float* __restrict__ rand_u,
                                  float* __restrict__ out)
{
    const int n   = blockIdx.x;
    const int tid = threadIdx.x;

    __shared__ double s_pxy[L_][M_][2];        // (px,py) interleaved, b128-readable
    __shared__ double s_part[2][4][NWAVE];     // [parity][value][wave], value-major
    __shared__ float  s_u[L_];

    const double PI_2 = 1.5707963267948966;

    // ---- trig init: pxy[l][m] = coef[m] * (cos, sin)(theta + inp*(m+1)*pi/2) ----
    #pragma unroll
    for (int i = 0; i < 9; ++i) {
        int j = tid + THREADS * i;
        int l = j / M_, m = j - l * M_;
        double a  = (double)inp[n * L_ + l] * ((double)(m + 1) * PI_2);
        double th = (double)theta[l * M_ + m];
        double sv, cv; sincos(th + a, &sv, &cv);
        double cf = (double)coef[m];
        s_pxy[l][m][0] = cf * cv;
        s_pxy[l][m][1] = cf * sv;
    }
    if (tid < L_) s_u[tid] = rand_u[tid * N_ + n];

    // ---- strided upper-triangle pair decode ----
    int pm[PPT], pk[PPT];
    double wgt[PPT];
    #pragma unroll
    for (int i = 0; i < PPT; ++i) {
        int p = tid + THREADS * i;
        if (p < NPAIR_UT) {
            int m = 0, r = p;
            while (r >= M_ - m) { r -= M_ - m; ++m; }
            pm[i] = m; pk[i] = m + r;
            wgt[i] = (r == 0) ? 1.0 : 2.0;
        } else { pm[i] = 0; pk[i] = 0; wgt[i] = 0.0; }
    }
    __syncthreads();

    // ---- register checkpoints: ckpt[s] = w * prod_{l'>=8(s+1)} T_l' ----
    double ckpt[5][PPT];
    {
        double C[PPT];
        #pragma unroll
        for (int i = 0; i < PPT; ++i) C[i] = wgt[i];
        #pragma unroll
        for (int s = 4; s >= 0; --s) {
            #pragma unroll
            for (int lp = 7; lp >= 0; --lp) {
                int l = 8 * (s + 1) + lp;              // 47 .. 8
                #pragma unroll
                for (int i = 0; i < PPT; ++i) {
                    double2 vm = *(const double2*)&s_pxy[l][pm[i]][0];
                    double2 vk = *(const double2*)&s_pxy[l][pk[i]][0];
                    C[i] *= vm.x * vk.x + vm.y * vk.y;
                }
            }
            #pragma unroll
            for (int i = 0; i < PPT; ++i) ckpt[s][i] = C[i];
        }
    }

    double G[PPT];
    #pragma unroll
    for (int i = 0; i < PPT; ++i) G[i] = 1.0;

    double denom = 0.0, initd = 1.0;
    float  myBit = 0.0f;

    #pragma unroll
    for (int seg = 0; seg < 6; ++seg) {
        // ---- segment stash: X[j][i], Y[j][i] for the 8 sites of this segment ----
        double X[8][PPT], Y[8][PPT];
        #pragma unroll
        for (int j = 0; j < 8; ++j) {
            int l2 = 8 * seg + j;
            #pragma unroll
            for (int i = 0; i < PPT; ++i) {
                double2 vm = *(const double2*)&s_pxy[l2][pm[i]][0];
                double2 vk = *(const double2*)&s_pxy[l2][pk[i]][0];
                X[j][i] = vm.x * vk.x;
                Y[j][i] = vm.y * vk.y;
            }
        }
        // ---- register expansion from stash: R[j] = w * S_{8seg+j+1} ----
        double R[8][PPT];
        #pragma unroll
        for (int i = 0; i < PPT; ++i)
            R[7][i] = (seg == 5) ? wgt[i] : ckpt[seg == 5 ? 0 : seg][i];
        #pragma unroll
        for (int j = 6; j >= 0; --j)
            #pragma unroll
            for (int i = 0; i < PPT; ++i)
                R[j][i] = R[j + 1][i] * (X[j + 1][i] + Y[j + 1][i]);

        // ---- 4 iterations x 2 speculative steps, all LDS-free ----
        #pragma unroll
        for (int half = 0; half < 4; ++half) {
            const int ls  = 2 * half;
            const int l   = 8 * seg + ls;
            const int par = half & 1;
            double n1L = 0.0, h0 = 0.0, h1 = 0.0, nT = 0.0;
            #pragma unroll
            for (int i = 0; i < PPT; ++i) {
                double t0 = G[i] * R[ls][i];
                double t1 = G[i] * R[ls + 1][i];
                n1L = fma(t0, Y[ls][i], n1L);
                if (seg == 0 && half == 0) nT = fma(t0, X[0][i], nT); // denom seed
                h0 = fma(t1 * X[ls][i], Y[ls + 1][i], h0);   // hypothesis bit_l = 0
                h1 = fma(t1 * Y[ls][i], Y[ls + 1][i], h1);   // hypothesis bit_l = 1
            }
            // butterfly: every lane ends with the identical full wave sum
            #pragma unroll
            for (int off = 1; off < 64; off <<= 1) {
                n1L += __shfl_xor(n1L, off, 64);
                h0  += __shfl_xor(h0,  off, 64);
                h1  += __shfl_xor(h1,  off, 64);
                if (seg == 0 && half == 0) nT += __shfl_xor(nT, off, 64);
            }
            const int wv = tid >> 6;
            if ((tid & 63) == 0) {
                s_part[par][0][wv] = n1L; s_part[par][1][wv] = h0;
                s_part[par][2][wv] = h1;
                if (seg == 0 && half == 0) s_part[par][3][wv] = nT;
            }
            __syncthreads();
            double2 a0 = *(const double2*)&s_part[par][0][0];
            double2 b0 = *(const double2*)&s_part[par][0][2];
            double2 a1 = *(const double2*)&s_part[par][1][0];
            double2 b1 = *(const double2*)&s_part[par][1][2];
            double2 a2 = *(const double2*)&s_part[par][2][0];
            double2 b2 = *(const double2*)&s_part[par][2][2];
            double sn1 = (a0.x + a0.y) + (b0.x + b0.y);
            double sh0 = (a1.x + a1.y) + (b1.x + b1.y);
            double sh1 = (a2.x + a2.y) + (b2.x + b2.y);
            if (seg == 0 && half == 0) {
                double2 a3 = *(const double2*)&s_part[par][3][0];
                double2 b3 = *(const double2*)&s_part[par][3][2];
                double snT = (a3.x + a3.y) + (b3.x + b3.y);
                denom = fabs(snT + sn1);
                initd = denom;
            }
            // two bit decisions, division-free (denom = <psi|psi> > 0)
            double v1 = fabs(sn1);
            int bitA   = ((double)s_u[l] * denom < v1) ? 1 : 0;
            denom      = bitA ? v1 : fabs(denom - sn1);
            double n1b = bitA ? sh1 : sh0;
            double v2  = fabs(n1b);
            int bitB   = ((double)s_u[l + 1] * denom < v2) ? 1 : 0;
            denom      = bitB ? v2 : fabs(denom - n1b);
            // fused two-step prefix update from stash
            #pragma unroll
            for (int i = 0; i < PPT; ++i) {
                double c0 = bitA ? Y[ls][i]     : X[ls][i];
                double c1 = bitB ? Y[ls + 1][i] : X[ls + 1][i];
                G[i] *= c0 * c1;
            }
            if (tid == l)     myBit = (float)bitA;
            if (tid == l + 1) myBit = (float)bitB;
        }
    }

    if (tid < L_)  out[n * L_ + tid] = myBit;                 // bits, one burst
    if (tid == 0)  out[N_ * L_ + n] = (float)(denom / initd); // P_m carried free
}

extern "C" void kernel_launch(void* const* d_in, const int* in_sizes, int n_in,
                              void* d_out, int out_size, void* d_ws, size_t ws_size,
                              hipStream_t stream) {
    const float* inp    = (const float*)d_in[0];   // (N,L)
    const float* theta  = (const float*)d_in[1];   // (L,M)
    const float* coef   = (const float*)d_in[2];   // (M,)
    const float* rand_u = (const float*)d_in[3];   // (L,N)
    float* out = (float*)d_out;                    // N*L bits then N probs
    mps_sample_kernel<<<N_, THREADS, 0, stream>>>(inp, theta, coef, rand_u, out);
}

// Round 7
// 82.488 us; speedup vs baseline: 1.2703x; 1.1555x over previous
//
#include <hip/hip_runtime.h>
#include <math.h>

#define M_ 48
#define L_ 48
#define N_ 256
#define THREADS 256
#define NWAVE 4
#define PPT 5                  // pairs per thread: one row-chunk of 5 consecutive k

// Compile-time chunk table: 255 chunks of (row m, k0=m+5j), dealt to lanes
// round-robin by (k0 & 7) so each vk load's 64 lanes spread over all 8 LDS
// bank groups (conflict-free); slot 255 is an all-weight-0 dummy.
struct ChunkTab { short cm[256]; short ck0[256]; };
constexpr ChunkTab make_tab() {
    ChunkTab t{};
    int bsz[8] = {};
    for (int m = 0; m < 48; ++m)
        for (int j = 0; 5 * j < 48 - m; ++j) bsz[(m + 5 * j) & 7]++;
    int slot = 0;
    for (int r = 0; r < 48; ++r)
        for (int b = 0; b < 8; ++b)
            if (bsz[b] > r) {
                int cnt = 0;
                for (int m = 0; m < 48; ++m)
                    for (int j = 0; 5 * j < 48 - m; ++j)
                        if (((m + 5 * j) & 7) == b) {
                            if (cnt == r) { t.cm[slot] = (short)m; t.ck0[slot] = (short)(m + 5 * j); }
                            ++cnt;
                        }
                ++slot;
            }
    for (; slot < 256; ++slot) { t.cm[slot] = 0; t.ck0[slot] = 127; }  // dummy: weights 0
    return t;
}
__device__ constexpr ChunkTab g_tab = make_tab();

// f64 DPP wave-sum: row_shr 1/2/4/8 then row_bcast15 (rows 1,3) and
// row_bcast31 (rows 2,3). Lane 63 ends with the 64-lane total. VALU-latency
// stages instead of ds_bpermute (R6 rounds were butterfly-latency-bound).
template<int CTRL, int RMASK>
__device__ __forceinline__ double dpp_add(double v) {
    int lo = __builtin_amdgcn_update_dpp(0, __double2loint(v), CTRL, RMASK, 0xf, true);
    int hi = __builtin_amdgcn_update_dpp(0, __double2hiint(v), CTRL, RMASK, 0xf, true);
    return v + __hiloint2double(hi, lo);
}
__device__ __forceinline__ double wave_sum63(double v) {
    v = dpp_add<0x111, 0xf>(v);   // row_shr:1
    v = dpp_add<0x112, 0xf>(v);   // row_shr:2
    v = dpp_add<0x114, 0xf>(v);   // row_shr:4
    v = dpp_add<0x118, 0xf>(v);   // row_shr:8  -> lane15/31/47/63 = row sums
    v = dpp_add<0x142, 0xa>(v);   // row_bcast15 -> lane31=r0+r1, lane63=r2+r3
    v = dpp_add<0x143, 0xc>(v);   // row_bcast31 -> lane63 = total
    return v;
}

__launch_bounds__(THREADS, 1)
__global__ void mps_sample_kernel(const float* __restrict__ inp,
                                  const float* __restrict__ theta,
                                  const float* __restrict__ coef,
                                  const float* __restrict__ rand_u,
                                  float* __restrict__ out)
{
    const int n   = blockIdx.x;
    const int tid = threadIdx.x;

    __shared__ double s_pxy[L_][M_][2];        // (px,py) interleaved, b128-readable
    __shared__ double s_part[2][4][NWAVE];     // [parity][value][wave]
    __shared__ float  s_u[L_];

    const double PI_2 = 1.5707963267948966;

    // ---- trig init: pxy[l][m] = coef[m] * (cos, sin)(theta + inp*(m+1)*pi/2) ----
    #pragma unroll
    for (int i = 0; i < 9; ++i) {
        int j = tid + THREADS * i;
        int l = j / M_, m = j - l * M_;
        double a  = (double)inp[n * L_ + l] * ((double)(m + 1) * PI_2);
        double th = (double)theta[l * M_ + m];
        double sv, cv; sincos(th + a, &sv, &cv);
        double cf = (double)coef[m];
        s_pxy[l][m][0] = cf * cv;
        s_pxy[l][m][1] = cf * sv;
    }
    if (tid < L_) s_u[tid] = rand_u[tid * N_ + n];

    // ---- row-chunk pair assignment: 5 pairs (cm, k0..k0+4) per thread ----
    const int cm = g_tab.cm[tid];
    const int k0 = g_tab.ck0[tid];
    int pk[PPT]; double wgt[PPT];
    #pragma unroll
    for (int i = 0; i < PPT; ++i) {
        int k = k0 + i;
        wgt[i] = (k > 47) ? 0.0 : ((k == cm) ? 1.0 : 2.0);
        pk[i]  = (k > 47) ? 47 : k;
    }
    __syncthreads();

    // ---- register checkpoints: ckpt[s] = w * prod_{l'>=8(s+1)} T_l' ----
    double ckpt[5][PPT];
    {
        double C[PPT];
        #pragma unroll
        for (int i = 0; i < PPT; ++i) C[i] = wgt[i];
        #pragma unroll
        for (int s = 4; s >= 0; --s) {
            #pragma unroll
            for (int lp = 7; lp >= 0; --lp) {
                int l = 8 * (s + 1) + lp;              // 47 .. 8
                double2 vm = *(const double2*)&s_pxy[l][cm][0];   // shared per thread
                #pragma unroll
                for (int i = 0; i < PPT; ++i) {
                    double2 vk = *(const double2*)&s_pxy[l][pk[i]][0];
                    C[i] *= vm.x * vk.x + vm.y * vk.y;
                }
            }
            #pragma unroll
            for (int i = 0; i < PPT; ++i) ckpt[s][i] = C[i];
        }
    }

    double G[PPT];
    #pragma unroll
    for (int i = 0; i < PPT; ++i) G[i] = 1.0;

    double denom = 0.0, initd = 1.0;
    float  myBit = 0.0f;

    #pragma unroll
    for (int seg = 0; seg < 6; ++seg) {
        // ---- segment stash: X[j][i], Y[j][i] (1 vm + 5 vk loads per site) ----
        double X[8][PPT], Y[8][PPT];
        #pragma unroll
        for (int j = 0; j < 8; ++j) {
            int l2 = 8 * seg + j;
            double2 vm = *(const double2*)&s_pxy[l2][cm][0];
            #pragma unroll
            for (int i = 0; i < PPT; ++i) {
                double2 vk = *(const double2*)&s_pxy[l2][pk[i]][0];
                X[j][i] = vm.x * vk.x;
                Y[j][i] = vm.y * vk.y;
            }
        }
        // ---- register expansion from stash: R[j] = w * S_{8seg+j+1} ----
        double R[8][PPT];
        #pragma unroll
        for (int i = 0; i < PPT; ++i)
            R[7][i] = (seg == 5) ? wgt[i] : ckpt[seg == 5 ? 0 : seg][i];
        #pragma unroll
        for (int j = 6; j >= 0; --j)
            #pragma unroll
            for (int i = 0; i < PPT; ++i)
                R[j][i] = R[j + 1][i] * (X[j + 1][i] + Y[j + 1][i]);

        // ---- 4 iterations x 2 speculative steps, DPP-reduced ----
        #pragma unroll
        for (int half = 0; half < 4; ++half) {
            const int ls  = 2 * half;
            const int l   = 8 * seg + ls;
            const int par = half & 1;
            double n1L = 0.0, h0 = 0.0, h1 = 0.0, nT = 0.0;
            #pragma unroll
            for (int i = 0; i < PPT; ++i) {
                double t0 = G[i] * R[ls][i];
                double t1 = G[i] * R[ls + 1][i];
                n1L = fma(t0, Y[ls][i], n1L);
                if (seg == 0 && half == 0) nT = fma(t0, X[0][i], nT); // denom seed
                h0 = fma(t1 * X[ls][i], Y[ls + 1][i], h0);   // hypothesis bit_l = 0
                h1 = fma(t1 * Y[ls][i], Y[ls + 1][i], h1);   // hypothesis bit_l = 1
            }
            n1L = wave_sum63(n1L);
            h0  = wave_sum63(h0);
            h1  = wave_sum63(h1);
            if (seg == 0 && half == 0) nT = wave_sum63(nT);
            if ((tid & 63) == 63) {                 // lane 63 holds wave totals
                const int wv = tid >> 6;
                s_part[par][0][wv] = n1L; s_part[par][1][wv] = h0;
                s_part[par][2][wv] = h1;
                if (seg == 0 && half == 0) s_part[par][3][wv] = nT;
            }
            __syncthreads();
            double2 a0 = *(const double2*)&s_part[par][0][0];
            double2 b0 = *(const double2*)&s_part[par][0][2];
            double2 a1 = *(const double2*)&s_part[par][1][0];
            double2 b1 = *(const double2*)&s_part[par][1][2];
            double2 a2 = *(const double2*)&s_part[par][2][0];
            double2 b2 = *(const double2*)&s_part[par][2][2];
            double sn1 = (a0.x + a0.y) + (b0.x + b0.y);
            double sh0 = (a1.x + a1.y) + (b1.x + b1.y);
            double sh1 = (a2.x + a2.y) + (b2.x + b2.y);
            if (seg == 0 && half == 0) {
                double2 a3 = *(const double2*)&s_part[par][3][0];
                double2 b3 = *(const double2*)&s_part[par][3][2];
                double snT = (a3.x + a3.y) + (b3.x + b3.y);
                denom = fabs(snT + sn1);
                initd = denom;
            }
            // two bit decisions, division-free (denom = <psi|psi> > 0)
            double v1 = fabs(sn1);
            int bitA   = ((double)s_u[l] * denom < v1) ? 1 : 0;
            denom      = bitA ? v1 : fabs(denom - sn1);
            double n1b = bitA ? sh1 : sh0;
            double v2  = fabs(n1b);
            int bitB   = ((double)s_u[l + 1] * denom < v2) ? 1 : 0;
            denom      = bitB ? v2 : fabs(denom - n1b);
            // fused two-step prefix update from stash
            #pragma unroll
            for (int i = 0; i < PPT; ++i) {
                double c0 = bitA ? Y[ls][i]     : X[ls][i];
                double c1 = bitB ? Y[ls + 1][i] : X[ls + 1][i];
                G[i] *= c0 * c1;
            }
            if (tid == l)     myBit = (float)bitA;
            if (tid == l + 1) myBit = (float)bitB;
        }
    }

    if (tid < L_)  out[n * L_ + tid] = myBit;                 // bits, one burst
    if (tid == 0)  out[N_ * L_ + n] = (float)(denom / initd); // P_m carried free
}

extern "C" void kernel_launch(void* const* d_in, const int* in_sizes, int n_in,
                              void* d_out, int out_size, void* d_ws, size_t ws_size,
                              hipStream_t stream) {
    const float* inp    = (const float*)d_in[0];   // (N,L)
    const float* theta  = (const float*)d_in[1];   // (L,M)
    const float* coef   = (const float*)d_in[2];   // (M,)
    const float* rand_u = (const float*)d_in[3];   // (L,N)
    float* out = (float*)d_out;                    // N*L bits then N probs
    mps_sample_kernel<<<N_, THREADS, 0, stream>>>(inp, theta, coef, rand_u, out);
}